// Round 1
// baseline (346.833 us; speedup 1.0000x reference)
//
#include <hip/hip_runtime.h>
#include <hip/hip_bf16.h>
#include <stdint.h>

// LSTM cell fused kernel for MI355X (gfx950).
// gates = [X | h_prev] @ [W_ih | W_hh]^T  (single GEMM, M=8192, N=4096, K=2048)
// Each block computes a 128(row) x 32(h) patch of ALL FOUR gates and applies
// the LSTM pointwise math in-kernel (no gates round-trip to HBM).

typedef __attribute__((ext_vector_type(8))) __bf16 bf16x8;
typedef __attribute__((ext_vector_type(8))) unsigned short u16x8;
typedef __attribute__((ext_vector_type(4))) float f32x4;

__device__ __forceinline__ unsigned short f2bf(float f) {
  union { float f; unsigned int u; } v; v.f = f;
  unsigned int u = v.u;
  unsigned int r = u + 0x7FFFu + ((u >> 16) & 1u);  // round-to-nearest-even
  return (unsigned short)(r >> 16);
}

__global__ void cvt_kernel(const float* __restrict__ src,
                           unsigned short* __restrict__ dst, int n4) {
  int i = blockIdx.x * blockDim.x + threadIdx.x;
  int stride = gridDim.x * blockDim.x;
  for (; i < n4; i += stride) {
    float4 v = ((const float4*)src)[i];
    ushort4 o;
    o.x = f2bf(v.x); o.y = f2bf(v.y); o.z = f2bf(v.z); o.w = f2bf(v.w);
    ((ushort4*)dst)[i] = o;
  }
}

#define GLOAD_LDS(gp, lofs)                                                    \
  __builtin_amdgcn_global_load_lds(                                            \
      (const __attribute__((address_space(1))) void*)(gp),                     \
      (__attribute__((address_space(3))) void*)(smem_raw + (lofs)), 16, 0, 0)

__global__ void lstm_fused(const unsigned short* __restrict__ Xb,
                           const unsigned short* __restrict__ Hb,
                           const unsigned short* __restrict__ Wihb,
                           const unsigned short* __restrict__ Whhb,
                           const float* __restrict__ bih,
                           const float* __restrict__ bhh,
                           const float* __restrict__ cprev,
                           float* __restrict__ out) {
  // 32 KB LDS: staging (A 16K + B 16K) aliased with epilogue exchange (64x128 f32)
  __shared__ __align__(16) char smem_raw[32768];
  unsigned short (*sA)[64] = (unsigned short (*)[64])smem_raw;           // [128][64]
  unsigned short (*sB)[64] = (unsigned short (*)[64])(smem_raw + 16384); // [128][64]
  float (*eps)[128] = (float (*)[128])smem_raw;                          // [64][128]

  const int tid = threadIdx.x;
  const int lane = tid & 63;
  const int wid = tid >> 6;
  const int wr = wid >> 1;  // 0..1 : wave row (64 rows each)
  const int wc = wid & 1;   // 0..1 : wave col (64 cols each)
  const int l15 = lane & 15;
  const int l4 = lane >> 4;

  const int m0 = blockIdx.x * 128;  // batch-row tile
  const int h0 = blockIdx.y * 32;   // hidden-unit tile

  // staging mapping: thread t -> row t>>3 (of 32-row issue), col (t&7)*8 elems
  const int srow = tid >> 3;
  const int scol = (tid & 7) << 3;

  f32x4 acc[4][4];
#pragma unroll
  for (int m = 0; m < 4; ++m)
#pragma unroll
    for (int n = 0; n < 4; ++n) {
      f32x4 z = {0.f, 0.f, 0.f, 0.f};
      acc[m][n] = z;
    }

  for (int k0 = 0; k0 < 2048; k0 += 64) {
    const unsigned short* As = (k0 < 1024) ? Xb : Hb;
    const unsigned short* Bs = (k0 < 1024) ? Wihb : Whhb;
    const int kk = k0 & 1023;
    // stage A tile [128][64] and B tile [128][64]; B row r -> W row
    // (r>>5)*1024 + h0 + (r&31)  (gate-blocked)
#pragma unroll
    for (int p = 0; p < 4; ++p) {
      const unsigned short* ga =
          As + (size_t)(m0 + p * 32 + srow) * 1024 + kk + scol;
      GLOAD_LDS(ga, p * 4096 + wid * 1024);
      const unsigned short* gb =
          Bs + (size_t)(p * 1024 + h0 + srow) * 1024 + kk + scol;
      GLOAD_LDS(gb, 16384 + p * 4096 + wid * 1024);
    }
    __syncthreads();
#pragma unroll
    for (int kk2 = 0; kk2 < 2; ++kk2) {
      bf16x8 afr[4], bfr[4];
#pragma unroll
      for (int m = 0; m < 4; ++m) {
        u16x8 t = *(const u16x8*)&sA[wr * 64 + m * 16 + l15][kk2 * 32 + l4 * 8];
        afr[m] = __builtin_bit_cast(bf16x8, t);
      }
#pragma unroll
      for (int n = 0; n < 4; ++n) {
        u16x8 t = *(const u16x8*)&sB[wc * 64 + n * 16 + l15][kk2 * 32 + l4 * 8];
        bfr[n] = __builtin_bit_cast(bf16x8, t);
      }
#pragma unroll
      for (int m = 0; m < 4; ++m)
#pragma unroll
        for (int n = 0; n < 4; ++n)
          acc[m][n] = __builtin_amdgcn_mfma_f32_16x16x32_bf16(afr[m], bfr[n],
                                                              acc[m][n], 0, 0, 0);
    }
    __syncthreads();
  }

  // ---- fused LSTM epilogue, two phases of 64 rows (eps aliases staging LDS) ----
#pragma unroll
  for (int phase = 0; phase < 2; ++phase) {
    if (wr == phase) {
#pragma unroll
      for (int m = 0; m < 4; ++m)
#pragma unroll
        for (int n = 0; n < 4; ++n)
#pragma unroll
          for (int r = 0; r < 4; ++r)
            eps[m * 16 + l4 * 4 + r][wc * 64 + n * 16 + l15] = acc[m][n][r];
    }
    __syncthreads();
    // acc col c corresponds to gate c>>5, h = h0 + (c&31)
#pragma unroll
    for (int it = 0; it < 8; ++it) {
      int idx = it * 256 + tid;  // 0..2047
      int h = idx & 31;
      int r = idx >> 5;  // 0..63
      int gh = h0 + h;
      size_t grow = (size_t)(m0 + phase * 64 + r);
      float vi = eps[r][h]       + bih[gh]         + bhh[gh];
      float vf = eps[r][32 + h]  + bih[1024 + gh]  + bhh[1024 + gh];
      float vg = eps[r][64 + h]  + bih[2048 + gh]  + bhh[2048 + gh];
      float vo = eps[r][96 + h]  + bih[3072 + gh]  + bhh[3072 + gh];
      float si = 1.f / (1.f + __expf(-vi));
      float sf = 1.f / (1.f + __expf(-vf));
      float tg = tanhf(vg);
      float so = 1.f / (1.f + __expf(-vo));
      float cp = cprev[grow * 1024 + gh];
      float ct = sf * cp + si * tg;
      float ht = so * tanhf(ct);
      out[grow * 1024 + gh] = ht;                       // h_t
      out[(size_t)8388608 + grow * 1024 + gh] = ct;     // c_t
    }
    __syncthreads();
  }
}

extern "C" void kernel_launch(void* const* d_in, const int* in_sizes, int n_in,
                              void* d_out, int out_size, void* d_ws, size_t ws_size,
                              hipStream_t stream) {
  const float* input  = (const float*)d_in[0];
  const float* h_prev = (const float*)d_in[1];
  const float* c_prev = (const float*)d_in[2];
  const float* W_ih   = (const float*)d_in[3];
  const float* b_ih   = (const float*)d_in[4];
  const float* W_hh   = (const float*)d_in[5];
  const float* b_hh   = (const float*)d_in[6];
  float* out = (float*)d_out;

  unsigned short* Xb   = (unsigned short*)d_ws;
  unsigned short* Hb   = Xb + (size_t)8192 * 1024;
  unsigned short* Wihb = Hb + (size_t)8192 * 1024;
  unsigned short* Whhb = Wihb + (size_t)4096 * 1024;
  // total ws use: (8192+8192+4096+4096)*1024*2 = 50,331,648 bytes

  cvt_kernel<<<1024, 256, 0, stream>>>(input, Xb, 8192 * 1024 / 4);
  cvt_kernel<<<1024, 256, 0, stream>>>(h_prev, Hb, 8192 * 1024 / 4);
  cvt_kernel<<<512, 256, 0, stream>>>(W_ih, Wihb, 4096 * 1024 / 4);
  cvt_kernel<<<512, 256, 0, stream>>>(W_hh, Whhb, 4096 * 1024 / 4);

  dim3 grid(64, 32);
  lstm_fused<<<grid, 256, 0, stream>>>(Xb, Hb, Wihb, Whhb, b_ih, b_hh, c_prev, out);
}

// Round 2
// 319.831 us; speedup vs baseline: 1.0844x; 1.0844x over previous
//
#include <hip/hip_runtime.h>
#include <hip/hip_bf16.h>
#include <stdint.h>

// LSTM cell fused kernel for MI355X (gfx950).
// gates = [X | h_prev] @ [W_ih | W_hh]^T  (single GEMM, M=8192, N=4096, K=2048)
// Round 2: (a) operand buffers stored PRE-SWIZZLED (chunk ct -> ct ^ (row&7)
// within each 64-elem K-tile) so linear global_load_lds + XOR'd ds_read_b128
// is bank-conflict-free; (b) all four f32->bf16 conversions fused into one
// dispatch.

typedef __attribute__((ext_vector_type(8))) __bf16 bf16x8;
typedef __attribute__((ext_vector_type(8))) unsigned short u16x8;
typedef __attribute__((ext_vector_type(4))) float f32x4;

__device__ __forceinline__ unsigned short f2bf(float f) {
  union { float f; unsigned int u; } v; v.f = f;
  unsigned int u = v.u;
  unsigned int r = u + 0x7FFFu + ((u >> 16) & 1u);  // round-to-nearest-even
  return (unsigned short)(r >> 16);
}

// One dispatch converts all four tensors; each tensor has row length 1024 f32
// (= 128 output chunks of 8 bf16 / 16 B). Output chunk position is swizzled:
// within each 8-chunk (64-element) K-tile, chunk ct stores at ct ^ (row & 7).
__global__ void cvt_swz(const float* __restrict__ s0, const float* __restrict__ s1,
                        const float* __restrict__ s2, const float* __restrict__ s3,
                        unsigned short* __restrict__ d0, unsigned short* __restrict__ d1,
                        unsigned short* __restrict__ d2, unsigned short* __restrict__ d3) {
  const float* src; unsigned short* dst; int nchunk;
  if (blockIdx.y == 0)      { src = s0; dst = d0; nchunk = 8192 * 128; }
  else if (blockIdx.y == 1) { src = s1; dst = d1; nchunk = 8192 * 128; }
  else if (blockIdx.y == 2) { src = s2; dst = d2; nchunk = 4096 * 128; }
  else                      { src = s3; dst = d3; nchunk = 4096 * 128; }
  int i = blockIdx.x * blockDim.x + threadIdx.x;
  int stride = gridDim.x * blockDim.x;
  for (; i < nchunk; i += stride) {
    int row = i >> 7;
    int cw = i & 127;        // chunk within row
    int tile = cw >> 3;      // 64-elem K-tile index
    int ct = cw & 7;         // chunk within tile
    float4 a = ((const float4*)src)[i * 2];
    float4 b = ((const float4*)src)[i * 2 + 1];
    u16x8 o;
    o[0] = f2bf(a.x); o[1] = f2bf(a.y); o[2] = f2bf(a.z); o[3] = f2bf(a.w);
    o[4] = f2bf(b.x); o[5] = f2bf(b.y); o[6] = f2bf(b.z); o[7] = f2bf(b.w);
    int oc = (row << 7) + (tile << 3) + (ct ^ (row & 7));
    *(u16x8*)&dst[(size_t)oc * 8] = o;
  }
}

#define GLOAD_LDS(gp, lofs)                                                    \
  __builtin_amdgcn_global_load_lds(                                            \
      (const __attribute__((address_space(1))) void*)(gp),                     \
      (__attribute__((address_space(3))) void*)(smem_raw + (lofs)), 16, 0, 0)

__global__ void lstm_fused(const unsigned short* __restrict__ Xb,
                           const unsigned short* __restrict__ Hb,
                           const unsigned short* __restrict__ Wihb,
                           const unsigned short* __restrict__ Whhb,
                           const float* __restrict__ bih,
                           const float* __restrict__ bhh,
                           const float* __restrict__ cprev,
                           float* __restrict__ out) {
  // 32 KB LDS: staging (A 16K + B 16K) aliased with epilogue exchange (64x128 f32)
  __shared__ __align__(16) char smem_raw[32768];
  unsigned short (*sA)[64] = (unsigned short (*)[64])smem_raw;           // [128][64]
  unsigned short (*sB)[64] = (unsigned short (*)[64])(smem_raw + 16384); // [128][64]
  float (*eps)[128] = (float (*)[128])smem_raw;                          // [64][128]

  const int tid = threadIdx.x;
  const int lane = tid & 63;
  const int wid = tid >> 6;
  const int wr = wid >> 1;  // 0..1 : wave row (64 rows each)
  const int wc = wid & 1;   // 0..1 : wave col (64 cols each)
  const int l15 = lane & 15;
  const int l4 = lane >> 4;

  const int m0 = blockIdx.x * 128;  // batch-row tile
  const int h0 = blockIdx.y * 32;   // hidden-unit tile

  // staging mapping: thread t -> row t>>3, 16B chunk (t&7) of the 64-elem tile
  const int srow = tid >> 3;
  const int scol = (tid & 7) << 3;

  f32x4 acc[4][4];
#pragma unroll
  for (int m = 0; m < 4; ++m)
#pragma unroll
    for (int n = 0; n < 4; ++n) {
      f32x4 z = {0.f, 0.f, 0.f, 0.f};
      acc[m][n] = z;
    }

  for (int k0 = 0; k0 < 2048; k0 += 64) {
    const unsigned short* As = (k0 < 1024) ? Xb : Hb;
    const unsigned short* Bs = (k0 < 1024) ? Wihb : Whhb;
    const int kk = k0 & 1023;
    // stage A tile [128][64] and B tile [128][64] (both already swizzled in ws);
    // B row r -> W row (r>>5)*1024 + h0 + (r&31)  (gate-blocked)
#pragma unroll
    for (int p = 0; p < 4; ++p) {
      const unsigned short* ga =
          As + (size_t)(m0 + p * 32 + srow) * 1024 + kk + scol;
      GLOAD_LDS(ga, p * 4096 + wid * 1024);
      const unsigned short* gb =
          Bs + (size_t)(p * 1024 + h0 + srow) * 1024 + kk + scol;
      GLOAD_LDS(gb, 16384 + p * 4096 + wid * 1024);
    }
    __syncthreads();
#pragma unroll
    for (int kk2 = 0; kk2 < 2; ++kk2) {
      bf16x8 afr[4], bfr[4];
#pragma unroll
      for (int m = 0; m < 4; ++m) {
        const int ra = wr * 64 + m * 16 + l15;
        const int ca = ((kk2 * 4 + l4) ^ (ra & 7)) << 3;  // swizzled chunk
        u16x8 t = *(const u16x8*)&sA[ra][ca];
        afr[m] = __builtin_bit_cast(bf16x8, t);
      }
#pragma unroll
      for (int n = 0; n < 4; ++n) {
        const int rb = wc * 64 + n * 16 + l15;
        const int cb = ((kk2 * 4 + l4) ^ (rb & 7)) << 3;  // swizzled chunk
        u16x8 t = *(const u16x8*)&sB[rb][cb];
        bfr[n] = __builtin_bit_cast(bf16x8, t);
      }
#pragma unroll
      for (int m = 0; m < 4; ++m)
#pragma unroll
        for (int n = 0; n < 4; ++n)
          acc[m][n] = __builtin_amdgcn_mfma_f32_16x16x32_bf16(afr[m], bfr[n],
                                                              acc[m][n], 0, 0, 0);
    }
    __syncthreads();
  }

  // ---- fused LSTM epilogue, two phases of 64 rows (eps aliases staging LDS) ----
#pragma unroll
  for (int phase = 0; phase < 2; ++phase) {
    if (wr == phase) {
#pragma unroll
      for (int m = 0; m < 4; ++m)
#pragma unroll
        for (int n = 0; n < 4; ++n)
#pragma unroll
          for (int r = 0; r < 4; ++r)
            eps[m * 16 + l4 * 4 + r][wc * 64 + n * 16 + l15] = acc[m][n][r];
    }
    __syncthreads();
    // eps col c corresponds to gate c>>5, h = h0 + (c&31)
#pragma unroll
    for (int it = 0; it < 8; ++it) {
      int idx = it * 256 + tid;  // 0..2047
      int h = idx & 31;
      int r = idx >> 5;  // 0..63
      int gh = h0 + h;
      size_t grow = (size_t)(m0 + phase * 64 + r);
      float vi = eps[r][h]       + bih[gh]         + bhh[gh];
      float vf = eps[r][32 + h]  + bih[1024 + gh]  + bhh[1024 + gh];
      float vg = eps[r][64 + h]  + bih[2048 + gh]  + bhh[2048 + gh];
      float vo = eps[r][96 + h]  + bih[3072 + gh]  + bhh[3072 + gh];
      float si = 1.f / (1.f + __expf(-vi));
      float sf = 1.f / (1.f + __expf(-vf));
      float tg = tanhf(vg);
      float so = 1.f / (1.f + __expf(-vo));
      float cp = cprev[grow * 1024 + gh];
      float ct = sf * cp + si * tg;
      float ht = so * tanhf(ct);
      out[grow * 1024 + gh] = ht;                       // h_t
      out[(size_t)8388608 + grow * 1024 + gh] = ct;     // c_t
    }
    __syncthreads();
  }
}

extern "C" void kernel_launch(void* const* d_in, const int* in_sizes, int n_in,
                              void* d_out, int out_size, void* d_ws, size_t ws_size,
                              hipStream_t stream) {
  const float* input  = (const float*)d_in[0];
  const float* h_prev = (const float*)d_in[1];
  const float* c_prev = (const float*)d_in[2];
  const float* W_ih   = (const float*)d_in[3];
  const float* b_ih   = (const float*)d_in[4];
  const float* W_hh   = (const float*)d_in[5];
  const float* b_hh   = (const float*)d_in[6];
  float* out = (float*)d_out;

  unsigned short* Xb   = (unsigned short*)d_ws;
  unsigned short* Hb   = Xb + (size_t)8192 * 1024;
  unsigned short* Wihb = Hb + (size_t)8192 * 1024;
  unsigned short* Whhb = Wihb + (size_t)4096 * 1024;
  // total ws use: (8192+8192+4096+4096)*1024*2 = 50,331,648 bytes

  dim3 cgrid(1024, 4);
  cvt_swz<<<cgrid, 256, 0, stream>>>(input, h_prev, W_ih, W_hh, Xb, Hb, Wihb, Whhb);

  dim3 grid(64, 32);
  lstm_fused<<<grid, 256, 0, stream>>>(Xb, Hb, Wihb, Whhb, b_ih, b_hh, c_prev, out);
}